// Round 1
// baseline (297.324 us; speedup 1.0000x reference)
//
#include <hip/hip_runtime.h>

#define OUT_N 11008
#define IN_K  4096
#define BATCH 32
#define NO    256          // outputs per block
#define KB    32           // k per LDS chunk
#define SEGS  32           // K segments across grid.y
#define KC    (IN_K / SEGS) // 128 k per block

// Prep: transpose x[b][k] -> xT[k][b] (contiguous in b for scalar loads),
// and initialize out[b][o] = bias[o] so the main kernel can atomically
// accumulate scale*partial on top.
__global__ __launch_bounds__(256) void prep_kernel(
    const float* __restrict__ x, const float* __restrict__ bias,
    float* __restrict__ xT, float* __restrict__ out)
{
    int i = blockIdx.x * 256 + threadIdx.x;
    if (i < BATCH * IN_K) {
        int b = i >> 12;           // / 4096
        int k = i & (IN_K - 1);
        xT[k * BATCH + b] = x[i];  // coalesced read, strided write (L2-resident)
    }
    if (i < BATCH * OUT_N) {
        int o = i % OUT_N;         // magic-mul div by constant
        out[i] = bias[o];
    }
}

// Main: block = 256 threads, owns NO=256 output rows x KC=128 k-slice.
// Thread t owns output o = o0 + t, accumulates all 32 batch rows.
// W tile staged in LDS transposed: lw[k][o_local], o-stride 257 so compute
// reads lw[k][t] are bank-conflict-free (consecutive lanes -> consecutive banks).
// x operand is wave-uniform -> scalar loads (s_load), SGPR src in v_fmac.
__global__ __launch_bounds__(256, 4) void lin2bit_kernel(
    const int* __restrict__ wq, const float* __restrict__ scale,
    const float* __restrict__ xT, float* __restrict__ out)
{
    __shared__ float lw[KB][NO + 1];   // [32][257] = 32.9 KB -> 4 blocks/CU

    const int t    = threadIdx.x;
    const int o0   = blockIdx.x * NO;
    const int kseg = blockIdx.y * KC;
    const int o    = o0 + t;

    float acc[BATCH];
#pragma unroll
    for (int b = 0; b < BATCH; ++b) acc[b] = 0.f;

    for (int chunk = 0; chunk < KC / KB; ++chunk) {
        const int k0 = kseg + chunk * KB;

        // Stage 256 rows x 32 ints -> LDS (transposed, converted to float).
        // 8 lanes cover one row's 128 B contiguous -> coalesced int4 loads.
#pragma unroll
        for (int j = 0; j < 8; ++j) {
            const int r = j * 32 + (t >> 3);
            const int c = (t & 7) * 4;
            const int4 v = *reinterpret_cast<const int4*>(
                wq + (size_t)(o0 + r) * IN_K + k0 + c);
            lw[c + 0][r] = (float)v.x;
            lw[c + 1][r] = (float)v.y;
            lw[c + 2][r] = (float)v.z;
            lw[c + 3][r] = (float)v.w;
        }
        __syncthreads();

        const float* __restrict__ xr = xT + (size_t)k0 * BATCH;
#pragma unroll 8
        for (int k = 0; k < KB; ++k) {
            const float w = lw[k][t];          // 1 ds_read_b32, conflict-free
#pragma unroll
            for (int b = 0; b < BATCH; ++b)    // 32 v_fmac, x from SGPRs
                acc[b] = fmaf(xr[k * BATCH + b], w, acc[b]);
        }
        __syncthreads();
    }

    const float s = scale[o];
#pragma unroll
    for (int b = 0; b < BATCH; ++b) {
        // hardware global_atomic_add_f32; 32 segments sum per output element
        unsafeAtomicAdd(out + (size_t)b * OUT_N + o, s * acc[b]);
    }
}

extern "C" void kernel_launch(void* const* d_in, const int* in_sizes, int n_in,
                              void* d_out, int out_size, void* d_ws, size_t ws_size,
                              hipStream_t stream) {
    const float* x     = (const float*)d_in[0];
    const int*   wq    = (const int*)d_in[1];
    const float* scale = (const float*)d_in[2];
    const float* bias  = (const float*)d_in[3];
    float* out = (float*)d_out;
    float* xT  = (float*)d_ws;   // 4096*32*4 = 512 KB scratch

    // covers both out init (352256) and xT transpose (131072)
    prep_kernel<<<dim3((BATCH * OUT_N + 255) / 256), 256, 0, stream>>>(x, bias, xT, out);
    lin2bit_kernel<<<dim3(OUT_N / NO, SEGS), 256, 0, stream>>>(wq, scale, xT, out);
}

// Round 2
// 256.325 us; speedup vs baseline: 1.1600x; 1.1600x over previous
//
#include <hip/hip_runtime.h>

#define OUT_N 11008
#define IN_K  4096
#define BATCH 32
#define SEGS  8
#define KSEG  (IN_K / SEGS)     // 512 k per block
#define OPB   64                // outputs per block (4 waves x 16)
#define XSTRIDE 520             // KSEG + 8 pad (bf16 elems) -> 2-way-free b128 reads

typedef __attribute__((ext_vector_type(8))) short short8;
typedef __attribute__((ext_vector_type(4))) float float4v;

// Prep: x fp32 -> bf16 (RNE) into ws; out[b][o] = bias[o] so main kernel
// can atomically accumulate K-segment partials on top.
__global__ __launch_bounds__(256) void prep_kernel(
    const float* __restrict__ x, const float* __restrict__ bias,
    unsigned short* __restrict__ xb, float* __restrict__ out)
{
    int i = blockIdx.x * 256 + threadIdx.x;
    if (i < BATCH * IN_K) {
        unsigned u = __builtin_bit_cast(unsigned, x[i]);
        unsigned r = u + 0x7FFFu + ((u >> 16) & 1u);   // round-to-nearest-even
        xb[i] = (unsigned short)(r >> 16);
    }
    if (i < BATCH * OUT_N) {
        out[i] = bias[i % OUT_N];
    }
}

// pack two fp32 (exact {-1,0,1}) into two bf16 by truncating mantissa:
// dst = { hi16(fhi), hi16(flo) }
__device__ __forceinline__ unsigned pkbf16(float fhi, float flo) {
    return __builtin_amdgcn_perm(__builtin_bit_cast(unsigned, fhi),
                                 __builtin_bit_cast(unsigned, flo),
                                 0x07060302u);
}

// Main: wave owns 16 outputs x 32 batch (2 MFMA acc tiles), block = 4 waves
// = 64 outputs, grid = (11008/64) x 8 K-segments. Weights stream global->VGPR
// (no reuse), x A-fragments come from a padded LDS slice.
__global__ __launch_bounds__(256, 4) void lin2bit_kernel(
    const int* __restrict__ wq, const float* __restrict__ scale,
    const unsigned short* __restrict__ xb, float* __restrict__ out)
{
    __shared__ unsigned short xs[BATCH][XSTRIDE];   // 33280 B -> 4 blocks/CU

    const int t    = threadIdx.x;
    const int lane = t & 63;
    const int wave = t >> 6;
    const int kseg = blockIdx.y * KSEG;

    // Stage x[0:32][kseg:kseg+512] bf16 -> LDS. 2048 16B-units, 8 iters.
    // 64 consecutive threads cover one row contiguously (coalesced, no conflicts).
#pragma unroll
    for (int it = 0; it < 8; ++it) {
        int idx = it * 256 + t;
        int b   = idx >> 6;
        int k8  = (idx & 63) * 8;
        uint4 v = *reinterpret_cast<const uint4*>(xb + b * IN_K + kseg + k8);
        *reinterpret_cast<uint4*>(&xs[b][k8]) = v;
    }
    __syncthreads();

    const int quad = lane >> 4;
    const int l16  = lane & 15;
    const int o    = blockIdx.x * OPB + wave * 16 + l16;

    const int* __restrict__ wrow = wq + (size_t)o * IN_K + kseg + quad * 8;
    const unsigned short* xrow0 = &xs[l16][quad * 8];
    const unsigned short* xrow1 = &xs[l16 + 16][quad * 8];

    float4v acc0 = {0.f, 0.f, 0.f, 0.f};
    float4v acc1 = {0.f, 0.f, 0.f, 0.f};

#pragma unroll 4
    for (int ki = 0; ki < KSEG; ki += 32) {
        // B-fragment: W[o][kseg+ki+quad*8 .. +8] as 8 ints -> 8 bf16 (exact)
        int4 w0 = *reinterpret_cast<const int4*>(wrow + ki);
        int4 w1 = *reinterpret_cast<const int4*>(wrow + ki + 4);
        uint4 bwu;
        bwu.x = pkbf16((float)w0.y, (float)w0.x);
        bwu.y = pkbf16((float)w0.w, (float)w0.z);
        bwu.z = pkbf16((float)w1.y, (float)w1.x);
        bwu.w = pkbf16((float)w1.w, (float)w1.z);
        short8 bfrag = __builtin_bit_cast(short8, bwu);

        // A-fragments: x[b=l16(+16)][k=quad*8+j] via ds_read_b128
        short8 a0 = *reinterpret_cast<const short8*>(xrow0 + ki);
        short8 a1 = *reinterpret_cast<const short8*>(xrow1 + ki);

        acc0 = __builtin_amdgcn_mfma_f32_16x16x32_bf16(a0, bfrag, acc0, 0, 0, 0);
        acc1 = __builtin_amdgcn_mfma_f32_16x16x32_bf16(a1, bfrag, acc1, 0, 0, 0);
    }

    // C/D layout: col(o) = lane&15, row(b) = quad*4 + reg
    const float s = scale[o];
    const int b0 = quad * 4;
#pragma unroll
    for (int r = 0; r < 4; ++r) {
        unsafeAtomicAdd(out + (size_t)(b0 + r)      * OUT_N + o, s * acc0[r]);
        unsafeAtomicAdd(out + (size_t)(b0 + r + 16) * OUT_N + o, s * acc1[r]);
    }
}

extern "C" void kernel_launch(void* const* d_in, const int* in_sizes, int n_in,
                              void* d_out, int out_size, void* d_ws, size_t ws_size,
                              hipStream_t stream) {
    const float* x     = (const float*)d_in[0];
    const int*   wq    = (const int*)d_in[1];
    const float* scale = (const float*)d_in[2];
    const float* bias  = (const float*)d_in[3];
    float* out = (float*)d_out;
    unsigned short* xb = (unsigned short*)d_ws;   // 32*4096*2 = 256 KB

    prep_kernel<<<dim3((BATCH * OUT_N + 255) / 256), 256, 0, stream>>>(x, bias, xb, out);
    lin2bit_kernel<<<dim3(OUT_N / OPB, SEGS), 256, 0, stream>>>(wq, scale, xb, out);
}